// Round 2
// baseline (118.252 us; speedup 1.0000x reference)
//
#include <hip/hip_runtime.h>

#define T_LEN 512
#define HDIM  32

// One wave = one batch element. lane = half*32 + h.
// Lane (h, half) owns output unit h and accumulates the partial dot over
// inputs j = half*16 .. half*16+15 (W chunk = 16 floats in VGPRs).
// Halves combine via shfl_xor(32); h-vector circulates through a wave-private
// 64-float LDS region laid out so the two halves' broadcast reads hit
// disjoint banks and the 64-lane publish write is a free 2-way alias.
__global__ void __launch_bounds__(256, 4) rnn_fused(
    const float* __restrict__ x,
    const float* __restrict__ W_ih,
    const float* __restrict__ W_hh,
    const float* __restrict__ b_ih,
    const float* __restrict__ b_hh,
    const float* __restrict__ fc_w,
    const float* __restrict__ fc_b,
    float* __restrict__ out)
{
    __shared__ __align__(16) float hreg[4][64];  // per-wave h copies (no barriers)
    __shared__ __align__(16) float xbuf[4][32];  // per-wave staged x chunk

    const int tid  = threadIdx.x;
    const int wv   = tid >> 6;
    const int lane = tid & 63;
    const int half = lane >> 5;      // which 16-wide input slice this lane sums
    const int h    = lane & 31;      // hidden unit owned by this lane
    const int b    = (blockIdx.x << 2) + wv;

    // W_hh[h][half*16 .. half*16+15] -> 4x float4 in VGPRs (one-time, cached)
    const float4* wrow = (const float4*)(W_hh + h * HDIM + half * 16);
    const float4 w0 = wrow[0], w1 = wrow[1], w2 = wrow[2], w3 = wrow[3];

    const float wih  = W_ih[h];
    const float bias = b_ih[h] + b_hh[h];
    const float* xrow = x + (size_t)b * T_LEN;

    float* hw = &hreg[wv][0];
    // half0 reads its j=0..15 at floats [0..15]; half1 reads j=16..31 at [48..63]
    const float4* hv4 = (const float4*)(hw + half * 48);
    const int wslot = (half << 5) + h;   // full 64-lane write, 2-way bank alias (free)

    hw[wslot] = 0.0f;                    // h0 = 0 (both copies)
    if (lane < 32) xbuf[wv][lane] = xrow[lane];   // stage x chunk 0

    float* xw = &xbuf[wv][0];
    float hn = 0.0f;
#pragma unroll 1
    for (int c = 0; c < T_LEN / 32; ++c) {
        float xn = 0.0f;
        const bool more = (c < T_LEN / 32 - 1);
        if (more && lane < 32) xn = xrow[(c + 1) * 32 + lane];  // prefetch next chunk
#pragma unroll 8
        for (int tc = 0; tc < 32; ++tc) {
            const float xt = xw[tc];                 // wave-uniform broadcast read
            const float4 h0 = hv4[0], h1 = hv4[1], h2 = hv4[2], h3 = hv4[3];
            float cx = w0.x * h0.x, cy = w0.y * h0.y, cz = w0.z * h0.z, cw = w0.w * h0.w;
            cx = __builtin_fmaf(w1.x, h1.x, cx);  cy = __builtin_fmaf(w1.y, h1.y, cy);
            cz = __builtin_fmaf(w1.z, h1.z, cz);  cw = __builtin_fmaf(w1.w, h1.w, cw);
            cx = __builtin_fmaf(w2.x, h2.x, cx);  cy = __builtin_fmaf(w2.y, h2.y, cy);
            cz = __builtin_fmaf(w2.z, h2.z, cz);  cw = __builtin_fmaf(w2.w, h2.w, cw);
            cx = __builtin_fmaf(w3.x, h3.x, cx);  cy = __builtin_fmaf(w3.y, h3.y, cy);
            cz = __builtin_fmaf(w3.z, h3.z, cz);  cw = __builtin_fmaf(w3.w, h3.w, cw);
            const float p  = (cx + cy) + (cz + cw);         // partial over this half's 16 inputs
            const float sp = __shfl_xor(p, 32, 64);         // partner half's partial
            const float y  = __builtin_fmaf(xt, wih, bias) + (p + sp);
            // tanh(y) = 1 - 2/(exp(2y)+1)
            const float e = __builtin_amdgcn_exp2f(y * 2.8853900817779268f);
            const float r = __builtin_amdgcn_rcpf(e + 1.0f);
            hn = __builtin_fmaf(-2.0f, r, 1.0f);
            hw[wslot] = hn;                                 // publish (in-order DS, same wave)
        }
        if (more && lane < 32) xw[lane] = xn;               // install prefetched chunk
    }

    // out[b] = sum_h h_T[h]*fc_w[h] + fc_b ; reduce half0's 32 lanes (h=0..31 once each)
    float v = hn * fc_w[h];
#pragma unroll
    for (int m = 16; m >= 1; m >>= 1) v += __shfl_xor(v, m, 64);
    if (lane == 0) out[b] = v + fc_b[0];
}

extern "C" void kernel_launch(void* const* d_in, const int* in_sizes, int n_in,
                              void* d_out, int out_size, void* d_ws, size_t ws_size,
                              hipStream_t stream) {
    const float* x    = (const float*)d_in[0];
    const float* W_ih = (const float*)d_in[1];
    const float* W_hh = (const float*)d_in[2];
    const float* b_ih = (const float*)d_in[3];
    const float* b_hh = (const float*)d_in[4];
    const float* fc_w = (const float*)d_in[5];
    const float* fc_b = (const float*)d_in[6];
    float* out = (float*)d_out;

    const int B = out_size;            // 4096
    dim3 grid(B / 4), block(256);      // 4 waves/block, 1 batch per wave
    hipLaunchKernelGGL(rnn_fused, grid, block, 0, stream,
                       x, W_ih, W_hh, b_ih, b_hh, fc_w, fc_b, out);
}

// Round 3
// 114.007 us; speedup vs baseline: 1.0372x; 1.0372x over previous
//
#include <hip/hip_runtime.h>

#define T_LEN 512

typedef float v2f __attribute__((ext_vector_type(2)));
typedef float v4f __attribute__((ext_vector_type(4)));

// One wave = 2 batch elements. lane = sub*32 + h.
// Lane owns output unit h of batch sub: full W_hh row (16 float2) in VGPRs,
// pinned there by an opaque asm so the compiler cannot rematerialize loads.
// h-vector circulates through wave-private LDS (broadcast reads, no barriers).
// Inner dot uses v_pk_fma_f32 (packed fp32) via __builtin_elementwise_fma.
__global__ void __launch_bounds__(256, 2) rnn_fused(
    const float* __restrict__ x,
    const float* __restrict__ W_ih,
    const float* __restrict__ W_hh,
    const float* __restrict__ b_ih,
    const float* __restrict__ b_hh,
    const float* __restrict__ fc_w,
    const float* __restrict__ fc_b,
    float* __restrict__ out)
{
    // stride 36 floats: 16B-aligned regions; halves' broadcast reads hit
    // disjoint banks ({4q..4q+3} vs {4q+4..4q+7}); 64-lane writes = 2/bank (free)
    __shared__ __align__(16) float hbuf[4][2][36];
    __shared__ __align__(16) float xbuf[4][2][34];

    const int tid  = threadIdx.x;
    const int wv   = tid >> 6;
    const int lane = tid & 63;
    const int sub  = lane >> 5;      // which batch within the wave
    const int h    = lane & 31;      // hidden unit owned by this lane
    const int b    = (blockIdx.x << 3) + (wv << 1) + sub;

    // W_hh row h -> 16 float2 in VGPRs (one-time gather, cached)
    const v2f* wrow = (const v2f*)(W_hh + h * 32);
    v2f w0 = wrow[0],  w1 = wrow[1],  w2 = wrow[2],  w3 = wrow[3];
    v2f w4 = wrow[4],  w5 = wrow[5],  w6 = wrow[6],  w7 = wrow[7];
    v2f w8 = wrow[8],  w9 = wrow[9],  wA = wrow[10], wB = wrow[11];
    v2f wC = wrow[12], wD = wrow[13], wE = wrow[14], wF = wrow[15];
    // opaque pass-through: values are no longer provably reloadable -> stay in VGPRs
    asm volatile("" : "+v"(w0), "+v"(w1), "+v"(w2), "+v"(w3),
                      "+v"(w4), "+v"(w5), "+v"(w6), "+v"(w7));
    asm volatile("" : "+v"(w8), "+v"(w9), "+v"(wA), "+v"(wB),
                      "+v"(wC), "+v"(wD), "+v"(wE), "+v"(wF));

    const float wih  = W_ih[h];
    const float bias = b_ih[h] + b_hh[h];
    const float* xrow = x + (size_t)b * T_LEN;

    float* hwp = &hbuf[wv][sub][0];
    float* xw  = &xbuf[wv][sub][0];
    const v4f* hv4 = (const v4f*)hwp;

    hwp[h] = 0.0f;          // h0 = 0
    xw[h]  = xrow[h];       // stage x chunk 0 (t = 0..31)

    float hn = 0.0f;
#pragma unroll 1
    for (int c = 0; c < T_LEN / 32; ++c) {
        float xn = 0.0f;
        const bool more = (c < T_LEN / 32 - 1);
        if (more) xn = xrow[(c + 1) * 32 + h];   // prefetch next x chunk
#pragma unroll
        for (int tc = 0; tc < 32; ++tc) {
            const float xt = xw[tc];             // broadcast read (uniform per half)
            const v4f q0 = hv4[0], q1 = hv4[1], q2 = hv4[2], q3 = hv4[3];
            const v4f q4 = hv4[4], q5 = hv4[5], q6 = hv4[6], q7 = hv4[7];
            const float xp = __builtin_fmaf(xt, wih, bias);
            v2f a0 = {xp, 0.0f};
            a0 = __builtin_elementwise_fma(w0, __builtin_shufflevector(q0, q0, 0, 1), a0);
            v2f a1 = w1 * __builtin_shufflevector(q0, q0, 2, 3);
            v2f a2 = w2 * __builtin_shufflevector(q1, q1, 0, 1);
            v2f a3 = w3 * __builtin_shufflevector(q1, q1, 2, 3);
            a0 = __builtin_elementwise_fma(w4, __builtin_shufflevector(q2, q2, 0, 1), a0);
            a1 = __builtin_elementwise_fma(w5, __builtin_shufflevector(q2, q2, 2, 3), a1);
            a2 = __builtin_elementwise_fma(w6, __builtin_shufflevector(q3, q3, 0, 1), a2);
            a3 = __builtin_elementwise_fma(w7, __builtin_shufflevector(q3, q3, 2, 3), a3);
            a0 = __builtin_elementwise_fma(w8, __builtin_shufflevector(q4, q4, 0, 1), a0);
            a1 = __builtin_elementwise_fma(w9, __builtin_shufflevector(q4, q4, 2, 3), a1);
            a2 = __builtin_elementwise_fma(wA, __builtin_shufflevector(q5, q5, 0, 1), a2);
            a3 = __builtin_elementwise_fma(wB, __builtin_shufflevector(q5, q5, 2, 3), a3);
            a0 = __builtin_elementwise_fma(wC, __builtin_shufflevector(q6, q6, 0, 1), a0);
            a1 = __builtin_elementwise_fma(wD, __builtin_shufflevector(q6, q6, 2, 3), a1);
            a2 = __builtin_elementwise_fma(wE, __builtin_shufflevector(q7, q7, 0, 1), a2);
            a3 = __builtin_elementwise_fma(wF, __builtin_shufflevector(q7, q7, 2, 3), a3);
            const v2f s0 = a0 + a1;              // v_pk_add_f32
            const v2f s1 = a2 + a3;
            const v2f s  = s0 + s1;
            const float y = s.x + s.y;
            // tanh(y) = 1 - 2/(exp(2y)+1)
            const float e = __builtin_amdgcn_exp2f(y * 2.8853900817779268f);
            const float r = __builtin_amdgcn_rcpf(e + 1.0f);
            hn = __builtin_fmaf(-2.0f, r, 1.0f);
            hwp[h] = hn;                         // publish h_t (in-order DS, same wave)
        }
        if (more) xw[h] = xn;                    // install prefetched x chunk
    }

    // out[b] = sum_h h_T[h]*fc_w[h] + fc_b ; butterfly within each 32-lane half
    float v = hn * fc_w[h];
#pragma unroll
    for (int m = 16; m >= 1; m >>= 1) v += __shfl_xor(v, m, 64);
    if (h == 0) out[b] = v + fc_b[0];
}

extern "C" void kernel_launch(void* const* d_in, const int* in_sizes, int n_in,
                              void* d_out, int out_size, void* d_ws, size_t ws_size,
                              hipStream_t stream) {
    const float* x    = (const float*)d_in[0];
    const float* W_ih = (const float*)d_in[1];
    const float* W_hh = (const float*)d_in[2];
    const float* b_ih = (const float*)d_in[3];
    const float* b_hh = (const float*)d_in[4];
    const float* fc_w = (const float*)d_in[5];
    const float* fc_b = (const float*)d_in[6];
    float* out = (float*)d_out;

    const int B = out_size;            // 4096
    dim3 grid(B / 8), block(256);      // 8 batch elements per 256-thread block
    hipLaunchKernelGGL(rnn_fused, grid, block, 0, stream,
                       x, W_ih, W_hh, b_ih, b_hh, fc_w, fc_b, out);
}

// Round 4
// 85.598 us; speedup vs baseline: 1.3815x; 1.3319x over previous
//
#include <hip/hip_runtime.h>

#define T_LEN 512

typedef float v2f __attribute__((ext_vector_type(2)));
typedef float v4f __attribute__((ext_vector_type(4)));

// One wave = 2 batch elements. lane = sub*32 + h.
// Lane owns output unit h of batch sub: full W_hh row (16 float2) in VGPRs.
// amdgpu_waves_per_eu(2,2) caps occupancy at the grid-imposed 2 waves/EU so the
// register allocator has no incentive to shrink arch-VGPR use (the observed
// failure mode of rounds 1-3: weights demoted to AGPRs, 32 v_accvgpr_read/step).
// h-vector circulates through wave-private LDS (broadcast reads, no barriers).
__global__ void __launch_bounds__(256) __attribute__((amdgpu_waves_per_eu(2, 2)))
rnn_fused(
    const float* __restrict__ x,
    const float* __restrict__ W_ih,
    const float* __restrict__ W_hh,
    const float* __restrict__ b_ih,
    const float* __restrict__ b_hh,
    const float* __restrict__ fc_w,
    const float* __restrict__ fc_b,
    float* __restrict__ out)
{
    // stride 36 floats: 16B-aligned regions; halves' broadcast reads hit
    // different banks; 64-lane writes are a free 2-way alias.
    __shared__ __align__(16) float hbuf[4][2][36];
    __shared__ __align__(16) float xbuf[4][2][34];

    const int tid  = threadIdx.x;
    const int wv   = tid >> 6;
    const int lane = tid & 63;
    const int sub  = lane >> 5;      // which batch within the wave
    const int h    = lane & 31;      // hidden unit owned by this lane
    const int b    = (blockIdx.x << 3) + (wv << 1) + sub;

    // W_hh row h -> 16 float2 in VGPRs (one-time gather, cached)
    const v2f* wrow = (const v2f*)(W_hh + h * 32);
    v2f w0 = wrow[0],  w1 = wrow[1],  w2 = wrow[2],  w3 = wrow[3];
    v2f w4 = wrow[4],  w5 = wrow[5],  w6 = wrow[6],  w7 = wrow[7];
    v2f w8 = wrow[8],  w9 = wrow[9],  wA = wrow[10], wB = wrow[11];
    v2f wC = wrow[12], wD = wrow[13], wE = wrow[14], wF = wrow[15];

    const float wih  = W_ih[h];
    const float bias = b_ih[h] + b_hh[h];
    const float* xrow = x + (size_t)b * T_LEN;

    float* hwp = &hbuf[wv][sub][0];
    float* xw  = &xbuf[wv][sub][0];
    const v4f* hv4 = (const v4f*)hwp;

    hwp[h] = 0.0f;          // h0 = 0
    xw[h]  = xrow[h];       // stage x chunk 0 (t = 0..31)

    float hn = 0.0f;
#pragma unroll 1
    for (int c = 0; c < T_LEN / 32; ++c) {
        // anti-AGPR insurance: weights must be live in arch VGPRs here; if the
        // allocator kept them there, these pins emit nothing.
        asm volatile("" : "+v"(w0), "+v"(w1), "+v"(w2), "+v"(w3),
                          "+v"(w4), "+v"(w5), "+v"(w6), "+v"(w7));
        asm volatile("" : "+v"(w8), "+v"(w9), "+v"(wA), "+v"(wB),
                          "+v"(wC), "+v"(wD), "+v"(wE), "+v"(wF));
        float xn = 0.0f;
        const bool more = (c < T_LEN / 32 - 1);
        if (more) xn = xrow[(c + 1) * 32 + h];   // prefetch next x chunk
#pragma unroll 8
        for (int tc = 0; tc < 32; ++tc) {
            const float xt = xw[tc];             // broadcast read (uniform per half)
            const v4f q0 = hv4[0], q1 = hv4[1], q2 = hv4[2], q3 = hv4[3];
            const v4f q4 = hv4[4], q5 = hv4[5], q6 = hv4[6], q7 = hv4[7];
            const float xp = __builtin_fmaf(xt, wih, bias);
            v2f a0 = {xp, 0.0f};
            a0 = __builtin_elementwise_fma(w0, __builtin_shufflevector(q0, q0, 0, 1), a0);
            v2f a1 = w1 * __builtin_shufflevector(q0, q0, 2, 3);
            v2f a2 = w2 * __builtin_shufflevector(q1, q1, 0, 1);
            v2f a3 = w3 * __builtin_shufflevector(q1, q1, 2, 3);
            a0 = __builtin_elementwise_fma(w4, __builtin_shufflevector(q2, q2, 0, 1), a0);
            a1 = __builtin_elementwise_fma(w5, __builtin_shufflevector(q2, q2, 2, 3), a1);
            a2 = __builtin_elementwise_fma(w6, __builtin_shufflevector(q3, q3, 0, 1), a2);
            a3 = __builtin_elementwise_fma(w7, __builtin_shufflevector(q3, q3, 2, 3), a3);
            a0 = __builtin_elementwise_fma(w8, __builtin_shufflevector(q4, q4, 0, 1), a0);
            a1 = __builtin_elementwise_fma(w9, __builtin_shufflevector(q4, q4, 2, 3), a1);
            a2 = __builtin_elementwise_fma(wA, __builtin_shufflevector(q5, q5, 0, 1), a2);
            a3 = __builtin_elementwise_fma(wB, __builtin_shufflevector(q5, q5, 2, 3), a3);
            a0 = __builtin_elementwise_fma(wC, __builtin_shufflevector(q6, q6, 0, 1), a0);
            a1 = __builtin_elementwise_fma(wD, __builtin_shufflevector(q6, q6, 2, 3), a1);
            a2 = __builtin_elementwise_fma(wE, __builtin_shufflevector(q7, q7, 0, 1), a2);
            a3 = __builtin_elementwise_fma(wF, __builtin_shufflevector(q7, q7, 2, 3), a3);
            const v2f s0 = a0 + a1;              // v_pk_add_f32
            const v2f s1 = a2 + a3;
            const v2f s  = s0 + s1;
            const float y = s.x + s.y;
            // tanh(y) = 1 - 2/(exp(2y)+1)
            const float e = __builtin_amdgcn_exp2f(y * 2.8853900817779268f);
            const float r = __builtin_amdgcn_rcpf(e + 1.0f);
            hn = __builtin_fmaf(-2.0f, r, 1.0f);
            hwp[h] = hn;                         // publish h_t (in-order DS, same wave)
        }
        if (more) xw[h] = xn;                    // install prefetched x chunk
    }

    // out[b] = sum_h h_T[h]*fc_w[h] + fc_b ; butterfly within each 32-lane half
    float v = hn * fc_w[h];
#pragma unroll
    for (int m = 16; m >= 1; m >>= 1) v += __shfl_xor(v, m, 64);
    if (h == 0) out[b] = v + fc_b[0];
}

extern "C" void kernel_launch(void* const* d_in, const int* in_sizes, int n_in,
                              void* d_out, int out_size, void* d_ws, size_t ws_size,
                              hipStream_t stream) {
    const float* x    = (const float*)d_in[0];
    const float* W_ih = (const float*)d_in[1];
    const float* W_hh = (const float*)d_in[2];
    const float* b_ih = (const float*)d_in[3];
    const float* b_hh = (const float*)d_in[4];
    const float* fc_w = (const float*)d_in[5];
    const float* fc_b = (const float*)d_in[6];
    float* out = (float*)d_out;

    const int B = out_size;            // 4096
    dim3 grid(B / 8), block(256);      // 8 batch elements per 256-thread block
    hipLaunchKernelGGL(rnn_fused, grid, block, 0, stream,
                       x, W_ih, W_hh, b_ih, b_hh, fc_w, fc_b, out);
}